// Round 9
// baseline (141.602 us; speedup 1.0000x reference)
//
#include <hip/hip_runtime.h>
#include <hip/hip_bf16.h>
#include <math.h>

#define BB 2
#define SS 2048
#define HH 16
#define DH 64
#define DQK 128
#define DD (HH*DH)
// Q folded scale = (1/sqrt(128)) * log2(e)  -> scores arrive in log2 domain
#define QS2   0.12751758f
// 8 * log2(e): fixed-max bias in log2 domain (cancels exactly in softmax)
#define EBIAS 11.5415605f

typedef _Float16 half8_t __attribute__((ext_vector_type(8)));
typedef _Float16 half4_t __attribute__((ext_vector_type(4)));
typedef float f32x4_t __attribute__((ext_vector_type(4)));
typedef float f32x4v __attribute__((ext_vector_type(4)));

// sin/cos in revolution domain: sin(2pi*frac(rev)) == sin(2pi*rev); v_sin/v_cos
// take revolutions natively (ISA: D=sin(S0*2pi)); fract keeps HW input range safe.
__device__ __forceinline__ void fsincos(float th, float* sn, float* cs) {
  float rev = th * 0.15915494309189535f;
  rev -= floorf(rev);
#if __has_builtin(__builtin_amdgcn_sinf) && __has_builtin(__builtin_amdgcn_cosf)
  *sn = __builtin_amdgcn_sinf(rev);
  *cs = __builtin_amdgcn_cosf(rev);
#else
  float ang = rev * 6.283185307179586f;
  *sn = __sinf(ang);
  *cs = __cosf(ang);
#endif
}

__device__ __forceinline__ float frcp(float v) {
#if __has_builtin(__builtin_amdgcn_rcpf)
  return __builtin_amdgcn_rcpf(v);
#else
  return 1.f / v;
#endif
}

// async global->LDS DMA, 16B/lane, LDS dest = uniform base + lane*16
__device__ __forceinline__ void dma16(const void* g, void* l) {
  __builtin_amdgcn_global_load_lds(
      (const __attribute__((address_space(1))) unsigned int*)g,
      (__attribute__((address_space(3))) unsigned int*)l, 16, 0, 0);
}

// Block per (stile, bh); bi = stile*32 + bh -> XCD = bh%8 matches flash's
// consumer XCD so K/V/Q writes have L2 affinity. Emits:
//   Q  row-major [bh][s][128], scale QS2 folded (log2-domain scores)
//   K  swizzled  [bh][ktile64][d8 0..15][key 0..63] 16B units
//   V  swizzled  [bh][ktile64][k8 0..7][dv 0..63]  16B units
__global__ __launch_bounds__(256) void gen_qkv(
    const float* __restrict__ x,
    const float* __restrict__ wq, const float* __restrict__ bq,
    const float* __restrict__ phq,
    const float* __restrict__ wk, const float* __restrict__ bk,
    const float* __restrict__ phk,
    const float* __restrict__ wv, const float* __restrict__ bv,
    _Float16* __restrict__ Qd, _Float16* __restrict__ Kd, _Float16* __restrict__ Vtd)
{
  int stile = blockIdx.x >> 5;
  int bh    = blockIdx.x & 31;
  int b = bh >> 4, h = bh & 15;
  int t = threadIdx.x;
  int sl = t >> 2;                 // 0..63 (key/row within tile)
  int dq = (t & 3) << 4;           // 0,16,32,48
  int s  = stile * 64 + sl;

  __shared__ _Float16 Vl[64 * 65]; // transpose buffer, odd pitch

  const float* xr = x + (((size_t)b * SS + s) * HH + h) * DH + dq;
  float tv = (float)s;
  int hd0 = h * DH + dq;
  _Float16 qc[16], qs[16], kc[16], ks[16];
#pragma unroll
  for (int g = 0; g < 4; g++) {
    f32x4v x4  = *(const f32x4v*)(xr + g * 4);
    f32x4v wq4 = *(const f32x4v*)(wq + hd0 + g * 4);
    f32x4v bq4 = *(const f32x4v*)(bq + hd0 + g * 4);
    f32x4v pq4 = *(const f32x4v*)(phq + hd0 + g * 4);
    f32x4v wk4 = *(const f32x4v*)(wk + hd0 + g * 4);
    f32x4v bk4 = *(const f32x4v*)(bk + hd0 + g * 4);
    f32x4v pk4 = *(const f32x4v*)(phk + hd0 + g * 4);
    f32x4v wv4 = *(const f32x4v*)(wv + hd0 + g * 4);
    f32x4v bv4 = *(const f32x4v*)(bv + hd0 + g * 4);
#pragma unroll
    for (int i2 = 0; i2 < 4; i2++) {
      int i = g * 4 + i2;
      float xv = x4[i2];
      {
        float th = xv * frcp(1.f + fabsf(wq4[i2])) + fmaf(tv, pq4[i2], bq4[i2]);
        float sn, cs; fsincos(th, &sn, &cs);
        qc[i] = (_Float16)(cs * QS2);
        qs[i] = (_Float16)(sn * QS2);
      }
      {
        float th = xv * frcp(1.f + fabsf(wk4[i2])) + fmaf(tv, pk4[i2], bk4[i2]);
        float sn, cs; fsincos(th, &sn, &cs);
        kc[i] = (_Float16)cs;
        ks[i] = (_Float16)sn;
      }
      {
        float th = xv * frcp(1.f + fabsf(wv4[i2])) + bv4[i2];
        float sn, cs; fsincos(th, &sn, &cs);
        Vl[(dq + i) * 65 + sl] = (_Float16)(cs + sn);
      }
    }
  }
  // Q row-major
  size_t qbase = ((size_t)bh * SS + s) * DQK;
#pragma unroll
  for (int i = 0; i < 2; i++) {
    *(half8_t*)(Qd + qbase + dq + i * 8)      = *(half8_t*)(&qc[i * 8]);
    *(half8_t*)(Qd + qbase + DH + dq + i * 8) = *(half8_t*)(&qs[i * 8]);
  }
  // K swizzled: cos dims d -> d8 = d/8; sin dims -> d8 = 8 + d/8
  {
    size_t ktb = ((size_t)bh * 32 + stile) * 8192;  // f16 base of 16KB tile
    int fo0 = (t & 3) * 2;
    *(half8_t*)(Kd + ktb + ((size_t)(fo0    ) * 64 + sl) * 8) = *(half8_t*)(&kc[0]);
    *(half8_t*)(Kd + ktb + ((size_t)(fo0 + 1) * 64 + sl) * 8) = *(half8_t*)(&kc[8]);
    *(half8_t*)(Kd + ktb + ((size_t)(fo0 + 8) * 64 + sl) * 8) = *(half8_t*)(&ks[0]);
    *(half8_t*)(Kd + ktb + ((size_t)(fo0 + 9) * 64 + sl) * 8) = *(half8_t*)(&ks[8]);
  }
  __syncthreads();
  // V swizzled: unit (k8, dv) = V[dv][keys k8*8..+7]; 2 units/thread, coalesced
#pragma unroll
  for (int i = 0; i < 2; i++) {
    int u = t * 2 + i;
    int dv = u & 63, ku = u >> 6;    // ku 0..7
    _Float16 tmp[8];
#pragma unroll
    for (int jj = 0; jj < 8; jj++) tmp[jj] = Vl[dv * 65 + ku * 8 + jj];
    *(half8_t*)(Vtd + (((size_t)bh * 32 + stile) * 8 + ku) * 512 + dv * 8) =
        *(half8_t*)tmp;
  }
}

// 1024 blocks = 32 qt x 32 bh, one q-tile each. qt = 31 - (bi>>5): LPT order.
// bh = bi & 31 -> XCD(bi%8) = bh%8. 4 waves = (qh) x (kh). Transposed-S:
// S^T = mfma(K,Q) with acc preloaded to -EBIAS, exp2 in-register, pack ->
// B-frag of 16x16x16 PV. K double-buffered in LDS via DMA (32KB total);
// V frags loaded straight from (swizzled) global into registers, issued
// BEFORE the K prefetch DMA so their waitcnt doesn't drain the prefetch.
__global__ __launch_bounds__(256) void flash_attn(
    const _Float16* __restrict__ Qd, const _Float16* __restrict__ Kd,
    const _Float16* __restrict__ Vtd,
    const float* __restrict__ wout, const float* __restrict__ bout,
    float* __restrict__ out)
{
  int qt = 31 - (blockIdx.x >> 5);
  int bh = blockIdx.x & 31;          // XCD = bh % 8
  int b  = bh >> 4, hh = bh & 15;
  int nch = qt + 1;
  int q0 = qt * 64;
  int wave = threadIdx.x >> 6;
  int lane = threadIdx.x & 63;
  int lm = lane & 15, lq = lane >> 4;
  int qh = wave >> 1;
  int kh = wave & 1;

  __shared__ __align__(16) _Float16 KB[2][8192];   // K dbuf: 16KB each

  const _Float16* Kg = Kd + (size_t)bh * 32 * 8192;
  const _Float16* Vg = Vtd + (size_t)bh * 32 * 4096;

  {  // preload K chunk 0 -> buf 0 (flies while Q frags load below)
#pragma unroll
    for (int i = 0; i < 4; i++)
      dma16(Kg + (size_t)(wave * 4 + i) * 512 + lane * 8, &KB[0][(wave * 4 + i) * 512]);
  }

  // Q B-frags resident: B[n=q][k=c*32+lq*8+j]
  const _Float16* Qb = Qd + ((size_t)bh * SS + q0 + qh * 32) * DQK;
  half8_t aq[2][4];
#pragma unroll
  for (int qtl = 0; qtl < 2; qtl++)
#pragma unroll
    for (int c = 0; c < 4; c++)
      aq[qtl][c] = *(const half8_t*)(Qb + (qtl * 16 + lm) * DQK + c * 32 + lq * 8);

  f32x4_t o[4][2];   // [dv-tile][q-tile], element = O^T[dt*16+lq*4+r][qtl*16+lm]
  float l[2] = {0.f, 0.f};
#pragma unroll
  for (int dt = 0; dt < 4; dt++)
#pragma unroll
    for (int qtl = 0; qtl < 2; qtl++) o[dt][qtl] = (f32x4_t){0.f, 0.f, 0.f, 0.f};

  const f32x4_t cinit = (f32x4_t){-EBIAS, -EBIAS, -EBIAS, -EBIAS};

  // per-wave V-frag global offset pattern (lane-dependent, kt-invariant)
  const _Float16* Vw = Vg + ((size_t)(lq >> 1) * 64 + lm) * 8 + (lq & 1) * 4 +
                       (size_t)kh * 4 * 64 * 8;

  for (int kt = 0; kt < nch; ++kt) {
    int bf = kt & 1;
    __syncthreads();   // drains DMA (vmcnt0 before barrier) + compute of kt-1

    // V frags for THIS chunk, from global (L2): issued before prefetch DMA
    half4_t vr[4][2];
    {
      const _Float16* vsrc = Vw + (size_t)kt * 4096;
#pragma unroll
      for (int dt = 0; dt < 4; dt++)
#pragma unroll
        for (int kg = 0; kg < 2; kg++)
          vr[dt][kg] = *(const half4_t*)(vsrc + ((size_t)kg * 2 * 64 + dt * 16) * 8);
    }

    if (kt + 1 < nch) {
      int nb = (kt + 1) & 1;
      const _Float16* gK = Kg + (size_t)(kt + 1) * 8192;
#pragma unroll
      for (int i = 0; i < 4; i++)
        dma16(gK + (size_t)(wave * 4 + i) * 512 + lane * 8, &KB[nb][(wave * 4 + i) * 512]);
    }

    const _Float16* lK = &KB[bf][0];
    int k0 = kt * 64;

    // S^T - EBIAS = K Q^T + (-EBIAS) : C-layout (key = lq*4+r, q = lm)
    f32x4_t cST[2][2];
    cST[0][0] = cST[0][1] = cST[1][0] = cST[1][1] = cinit;
#pragma unroll
    for (int c = 0; c < 4; c++) {
      half8_t k0f = *(const half8_t*)(lK + ((size_t)(c * 4 + lq) * 64 + kh * 32 + lm) * 8);
      half8_t k1f = *(const half8_t*)(lK + ((size_t)(c * 4 + lq) * 64 + kh * 32 + 16 + lm) * 8);
      cST[0][0] = __builtin_amdgcn_mfma_f32_16x16x32_f16(k0f, aq[0][c], cST[0][0], 0, 0, 0);
      cST[0][1] = __builtin_amdgcn_mfma_f32_16x16x32_f16(k0f, aq[1][c], cST[0][1], 0, 0, 0);
      cST[1][0] = __builtin_amdgcn_mfma_f32_16x16x32_f16(k1f, aq[0][c], cST[1][0], 0, 0, 0);
      cST[1][1] = __builtin_amdgcn_mfma_f32_16x16x32_f16(k1f, aq[1][c], cST[1][1], 0, 0, 0);
    }

    // p = 2^(s2) in-register; pack -> B-frags (B[n=q=lm][k=lq*4+i])
    bool maskit = (kt == nch - 1);
    half4_t pb[2][2];
#pragma unroll
    for (int ktl = 0; ktl < 2; ktl++)
#pragma unroll
      for (int qtl = 0; qtl < 2; qtl++) {
        float pf[4];
#pragma unroll
        for (int r = 0; r < 4; r++) {
          float sv = cST[ktl][qtl][r];
          if (maskit) {
            int key  = k0 + kh * 32 + ktl * 16 + lq * 4 + r;
            int qrow = q0 + qh * 32 + qtl * 16 + lm;
            if (key > qrow) sv = -1e30f;
          }
          pf[r] = __builtin_exp2f(sv);
          l[qtl] += pf[r];
        }
        pb[ktl][qtl] = (half4_t){(_Float16)pf[0], (_Float16)pf[1],
                                 (_Float16)pf[2], (_Float16)pf[3]};
      }

    // O^T += V^T P^T : A = V^T frag (m=dv, k=key lq*4+i), 16 MFMA 16x16x16
#pragma unroll
    for (int dt = 0; dt < 4; dt++)
#pragma unroll
      for (int kg = 0; kg < 2; kg++) {
        o[dt][0] = __builtin_amdgcn_mfma_f32_16x16x16f16(vr[dt][kg], pb[kg][0], o[dt][0], 0, 0, 0);
        o[dt][1] = __builtin_amdgcn_mfma_f32_16x16x16f16(vr[dt][kg], pb[kg][1], o[dt][1], 0, 0, 0);
      }
  }

  // reduce l over lq groups (keys): all lanes end with l for q = qtl*16+lm
#pragma unroll
  for (int qtl = 0; qtl < 2; qtl++) {
    l[qtl] += __shfl_xor(l[qtl], 16);
    l[qtl] += __shfl_xor(l[qtl], 32);
  }

  // combine kh halves + normalize via LDS overlaid on the K buffers
  // (all K reads done after final barrier), then epilogue.
  float* Of = (float*)&KB[0][0];        // [row][pitch 68], 17664 B < 32768 B
  float* Lf = Of + 64 * 68;
  __syncthreads();
  if (kh == 1) {
#pragma unroll
    for (int qtl = 0; qtl < 2; qtl++) {
      int row = qh * 32 + qtl * 16 + lm;
#pragma unroll
      for (int dt = 0; dt < 4; dt++)
#pragma unroll
        for (int r = 0; r < 4; r++)
          Of[row * 68 + dt * 16 + lq * 4 + r] = o[dt][qtl][r];
      if (lq == 0) Lf[row] = l[qtl];
    }
  }
  __syncthreads();
  if (kh == 0) {
#pragma unroll
    for (int qtl = 0; qtl < 2; qtl++) {
      int row = qh * 32 + qtl * 16 + lm;
      float rl = frcp(l[qtl] + Lf[row]);
#pragma unroll
      for (int dt = 0; dt < 4; dt++)
#pragma unroll
        for (int r = 0; r < 4; r++) {
          int idx = row * 68 + dt * 16 + lq * 4 + r;
          Of[idx] = (o[dt][qtl][r] + Of[idx]) * rl;
        }
    }
  }
  __syncthreads();
  {
    int dcol = hh * DH + lane;
    float iw = frcp(1.f + fabsf(wout[dcol]));
    float bo = bout[dcol];
#pragma unroll
    for (int rr = 0; rr < 16; rr++) {
      int row = wave * 16 + rr;
      float th = Of[row * 68 + lane] * iw + bo;
      float sn, cs; fsincos(th, &sn, &cs);
      out[((size_t)b * SS + q0 + row) * DD + dcol] = cs + sn;
    }
  }
}

extern "C" void kernel_launch(void* const* d_in, const int* in_sizes, int n_in,
                              void* d_out, int out_size, void* d_ws, size_t ws_size,
                              hipStream_t stream) {
  (void)in_sizes; (void)n_in; (void)out_size; (void)ws_size;
  const float* x   = (const float*)d_in[0];
  const float* wq  = (const float*)d_in[1];
  const float* bq  = (const float*)d_in[2];
  const float* phq = (const float*)d_in[3];
  const float* wk  = (const float*)d_in[4];
  const float* bk  = (const float*)d_in[5];
  const float* phk = (const float*)d_in[6];
  const float* wv  = (const float*)d_in[7];
  const float* bv  = (const float*)d_in[8];
  const float* wo  = (const float*)d_in[9];
  const float* bo  = (const float*)d_in[10];

  _Float16* Qd  = (_Float16*)d_ws;
  _Float16* Kd  = Qd + (size_t)BB * HH * SS * DQK;
  _Float16* Vtd = Kd + (size_t)BB * HH * SS * DQK;

  gen_qkv<<<BB * HH * (SS / 64), 256, 0, stream>>>(
      x, wq, bq, phq, wk, bk, phk, wv, bv, Qd, Kd, Vtd);
  flash_attn<<<32 * 32, 256, 0, stream>>>(
      Qd, Kd, Vtd, wo, bo, (float*)d_out);
}